// Round 7
// baseline (455.868 us; speedup 1.0000x reference)
//
#include <hip/hip_runtime.h>

#define LOG2E 1.4426950408889634f

typedef __attribute__((ext_vector_type(8))) short short8;
typedef __attribute__((ext_vector_type(4))) float f32x4;
typedef __attribute__((ext_vector_type(16))) float f32x16;
typedef __attribute__((ext_vector_type(4))) unsigned u32x4;

__device__ inline unsigned short f2bf(float f) {
  unsigned u = __float_as_uint(f);
  u += 0x7fffu + ((u >> 16) & 1u);
  return (unsigned short)(u >> 16);
}

#define MFMA16(a, b, c) __builtin_amdgcn_mfma_f32_16x16x32_bf16((a), (b), (c), 0, 0, 0)
#define MFMA32(a, b, c) __builtin_amdgcn_mfma_f32_32x32x16_bf16((a), (b), (c), 0, 0, 0)

#define GLDS16(gp, lp)                                                              \
  __builtin_amdgcn_global_load_lds((const __attribute__((address_space(1))) void*)(gp), \
                                   (__attribute__((address_space(3))) void*)(lp), 16, 0, 0)

__device__ inline f32x4 zero4() {
  f32x4 z = {0.f, 0.f, 0.f, 0.f};
  return z;
}
__device__ inline f32x16 zero16() {
  f32x16 z = {0.f, 0.f, 0.f, 0.f, 0.f, 0.f, 0.f, 0.f, 0.f, 0.f, 0.f, 0.f, 0.f, 0.f, 0.f, 0.f};
  return z;
}
// dst.lo16 = bf16(a), dst.hi16 = bf16(b)  (RNE, same bits as f2bf)
__device__ inline unsigned cvtpk_bf16(float a, float b) {
  unsigned r;
  asm("v_cvt_pk_bf16_f32 %0, %1, %2" : "=v"(r) : "v"(a), "v"(b));
  return r;
}
// after: a = [a.lo32lanes, b.lo32lanes], b = [a.hi32lanes, b.hi32lanes]
__device__ inline void plswap(unsigned& a, unsigned& b) {
  asm("v_permlane32_swap_b32 %0, %1" : "+v"(a), "+v"(b));
}

// ---------------------------------------------------------------- cast fp32 -> bf16, WEIGHTS ONLY (Q/E casts fused into consumers)
__global__ __launch_bounds__(256) void k_cast4(
    const float* __restrict__ wq, const float* __restrict__ wo,
    const float* __restrict__ wb, const float* __restrict__ wa,
    unsigned short* __restrict__ wqo, unsigned short* __restrict__ woo,
    unsigned short* __restrict__ wbo, unsigned short* __restrict__ wao) {
  int i = (blockIdx.x * 256 + threadIdx.x) * 4;
  const float* src;
  unsigned short* dst;
  int off;
  if (i < 1048576) { src = wq; dst = wqo; off = i; }
  else if (i < 2097152) { src = wo; dst = woo; off = i - 1048576; }
  else if (i < 2621440) { src = wb; dst = wbo; off = i - 2097152; }
  else { src = wa; dst = wao; off = i - 2621440; }
  float4 v = *(const float4*)(src + off);
  unsigned lo = (unsigned)f2bf(v.x) | ((unsigned)f2bf(v.y) << 16);
  unsigned hi = (unsigned)f2bf(v.z) | ((unsigned)f2bf(v.w) << 16);
  *(uint2*)(dst + off) = make_uint2(lo, hi);
}

// ---------------------------------------------------------------- K1: q = query(fp32) @ Wq^T (scaled by log2e/8) -> (B,H,SQ,64) bf16
// A side reads fp32 directly (reg-stage + cvt_pk + ds_write_b128) -- kills the
// 48 MB Q cast round-trip. B side stays global_load_lds.
__global__ __launch_bounds__(256, 2) void k_qproj(const float* __restrict__ A,
                                                  const unsigned short* __restrict__ Bw,
                                                  unsigned short* __restrict__ Qout) {
  __shared__ __align__(16) short As[128 * 32];
  __shared__ __align__(16) short Bs[128 * 32];
  const int K = 1024;
  int tid = threadIdx.x;
  int w = tid >> 6, lane = tid & 63, quad = lane >> 4, c = lane & 15;
  int m0 = blockIdx.x * 128, n0 = blockIdx.y * 128;
  int wm = (w >> 1) * 64, wn = (w & 1) * 64;
  int rsub = lane >> 2, csub = (lane & 3) * 8;
  f32x4 acc[4][4];
#pragma unroll
  for (int i = 0; i < 4; i++)
#pragma unroll
    for (int j = 0; j < 4; j++) acc[i][j] = zero4();

  for (int k0 = 0; k0 < K; k0 += 32) {
    // A: fp32 -> bf16 reg-staged (rows seg*16+rsub, cols csub..csub+7)
#pragma unroll
    for (int i = 0; i < 2; i++) {
      int seg = w * 2 + i;
      const float* Ap = A + (size_t)(m0 + seg * 16 + rsub) * K + k0 + csub;
      float4 va = *(const float4*)Ap;
      float4 vb2 = *(const float4*)(Ap + 4);
      u32x4 pk = {cvtpk_bf16(va.x, va.y), cvtpk_bf16(va.z, va.w),
                  cvtpk_bf16(vb2.x, vb2.y), cvtpk_bf16(vb2.z, vb2.w)};
      *(u32x4*)((char*)As + seg * 1024 + lane * 16) = pk;
    }
    // B: bf16 via global_load_lds
#pragma unroll
    for (int i = 0; i < 2; i++) {
      int seg = w * 2 + i;
      int bo = seg * 1024 + lane * 16;
      int row = bo >> 6, col = (bo & 63) >> 1;
      GLDS16(Bw + (size_t)(n0 + row) * K + k0 + col, (char*)Bs + seg * 1024);
    }
    __syncthreads();
    short8 af[4], bfr[4];
#pragma unroll
    for (int i = 0; i < 4; i++) {
      af[i] = *(const short8*)&As[(wm + i * 16 + c) * 32 + quad * 8];
      bfr[i] = *(const short8*)&Bs[(wn + i * 16 + c) * 32 + quad * 8];
    }
#pragma unroll
    for (int mi = 0; mi < 4; mi++)
#pragma unroll
      for (int ni = 0; ni < 4; ni++) acc[mi][ni] = MFMA16(af[mi], bfr[ni], acc[mi][ni]);
    __syncthreads();
  }
  const float scale = 0.125f * LOG2E;
#pragma unroll
  for (int mi = 0; mi < 4; mi++) {
    int rowb = m0 + wm + mi * 16 + quad * 4;
#pragma unroll
    for (int ni = 0; ni < 4; ni++) {
      int col = n0 + wn + ni * 16 + c;
      int h = col >> 6, d = col & 63;
#pragma unroll
      for (int r = 0; r < 4; r++) {
        int row = rowb + r;
        int b = row >> 11, sq = row & 2047;
        Qout[(((size_t)(b * 16 + h)) * 2048 + sq) * 64 + d] = f2bf(acc[mi][ni][r] * scale);
      }
    }
  }
}

// ---------------------------------------------------------------- K2: c = enc(fp32) @ Wkva^T, LayerNorm -> [16384,256] bf16
// E side reads fp32 directly (kills the 96 MB E cast round-trip).
__global__ __launch_bounds__(256, 2) void k_cln(const float* __restrict__ E,
                                                const unsigned short* __restrict__ Wa,
                                                const float* __restrict__ g, const float* __restrict__ bb,
                                                unsigned short* __restrict__ Cout) {
  __shared__ __align__(16) short As[64 * 32];
  __shared__ __align__(16) short Bs[256 * 32];
  __shared__ float redS[4][64], redQ[4][64];
  __shared__ float gS[256], bS[256];
  const int K = 1024;
  int tid = threadIdx.x;
  int w = tid >> 6, lane = tid & 63, quad = lane >> 4, c = lane & 15;
  int m0 = blockIdx.x * 64;
  int rsub = lane >> 2, csub = (lane & 3) * 8;
  gS[tid] = g[tid];
  bS[tid] = bb[tid];
  f32x4 acc[4][4];
#pragma unroll
  for (int i = 0; i < 4; i++)
#pragma unroll
    for (int j = 0; j < 4; j++) acc[i][j] = zero4();

  for (int k0 = 0; k0 < K; k0 += 32) {
    {
      const float* Ep = E + (size_t)(m0 + w * 16 + rsub) * K + k0 + csub;
      float4 va = *(const float4*)Ep;
      float4 vb2 = *(const float4*)(Ep + 4);
      u32x4 pk = {cvtpk_bf16(va.x, va.y), cvtpk_bf16(va.z, va.w),
                  cvtpk_bf16(vb2.x, vb2.y), cvtpk_bf16(vb2.z, vb2.w)};
      *(u32x4*)((char*)As + w * 1024 + lane * 16) = pk;
    }
#pragma unroll
    for (int i = 0; i < 4; i++) {
      int seg = w * 4 + i;
      int bo = seg * 1024 + lane * 16;
      int row = bo >> 6, col = (bo & 63) >> 1;
      GLDS16(Wa + (size_t)row * K + k0 + col, (char*)Bs + seg * 1024);
    }
    __syncthreads();
    short8 af[4], bfr[4];
#pragma unroll
    for (int i = 0; i < 4; i++) {
      af[i] = *(const short8*)&As[(i * 16 + c) * 32 + quad * 8];
      bfr[i] = *(const short8*)&Bs[(w * 64 + i * 16 + c) * 32 + quad * 8];
    }
#pragma unroll
    for (int mi = 0; mi < 4; mi++)
#pragma unroll
      for (int ni = 0; ni < 4; ni++) acc[mi][ni] = MFMA16(af[mi], bfr[ni], acc[mi][ni]);
    __syncthreads();
  }
  float ps[4][4], pq[4][4];
#pragma unroll
  for (int mi = 0; mi < 4; mi++)
#pragma unroll
    for (int r = 0; r < 4; r++) {
      float s = 0.f, q = 0.f;
#pragma unroll
      for (int ni = 0; ni < 4; ni++) {
        float x = acc[mi][ni][r];
        s += x;
        q += x * x;
      }
      for (int m = 1; m < 16; m <<= 1) {
        s += __shfl_xor(s, m, 64);
        q += __shfl_xor(q, m, 64);
      }
      ps[mi][r] = s;
      pq[mi][r] = q;
    }
  if (c == 0) {
#pragma unroll
    for (int mi = 0; mi < 4; mi++)
#pragma unroll
      for (int r = 0; r < 4; r++) {
        int row = mi * 16 + quad * 4 + r;
        redS[w][row] = ps[mi][r];
        redQ[w][row] = pq[mi][r];
      }
  }
  __syncthreads();
  float muv[4][4], rsv[4][4];
#pragma unroll
  for (int mi = 0; mi < 4; mi++)
#pragma unroll
    for (int r = 0; r < 4; r++) {
      int row = mi * 16 + quad * 4 + r;
      float S = redS[0][row] + redS[1][row] + redS[2][row] + redS[3][row];
      float Q = redQ[0][row] + redQ[1][row] + redQ[2][row] + redQ[3][row];
      float mu = S * (1.f / 256.f);
      float var = Q * (1.f / 256.f) - mu * mu;
      muv[mi][r] = mu;
      rsv[mi][r] = rsqrtf(var + 1e-5f);
    }
#pragma unroll
  for (int mi = 0; mi < 4; mi++)
#pragma unroll
    for (int ni = 0; ni < 4; ni++) {
      int col = w * 64 + ni * 16 + c;
#pragma unroll
      for (int r = 0; r < 4; r++) {
        int row = m0 + mi * 16 + quad * 4 + r;
        float y = (acc[mi][ni][r] - muv[mi][r]) * rsv[mi][r] * gS[col] + bS[col];
        Cout[(size_t)row * 256 + col] = f2bf(y);
      }
    }
}

// ---------------------------------------------------------------- K3: kv = c_ln @ Wkvb^T -> K, V in attn fragment-major tiles
//  K: per bh, per 64-key tile: [(half*4 + ds)*64 + (key&31) + 32*((d>>3)&1)]*8 + (d&7)
//  V: [(dt*4 + s)*64 + (d&31) + 32*((k>>3)&1)]*8 + (k&7)
// R7: V-store packed -- a lane's 4 r-values are 4 consecutive j-slots
// (j = (quad&1)*4 + r), so one 8B uint2 store replaces 4 scalar ushort scatter
// stores (old: 2B per 16B segment = 1/8 write efficiency on 32 MB; new: quad
// pairs complete full 16B segments).
__global__ __launch_bounds__(256, 2) void k_kv(const unsigned short* __restrict__ A,
                                               const unsigned short* __restrict__ Bw,
                                               unsigned short* __restrict__ Kb,
                                               unsigned short* __restrict__ Vb) {
  __shared__ __align__(16) short As[128 * 32];
  __shared__ __align__(16) short Bs[128 * 32];
  const int K = 256;
  int tid = threadIdx.x;
  int w = tid >> 6, lane = tid & 63, quad = lane >> 4, c = lane & 15;
  int m0 = blockIdx.x * 128, n0 = blockIdx.y * 128;
  int wm = (w >> 1) * 64, wn = (w & 1) * 64;
  f32x4 acc[4][4];
#pragma unroll
  for (int i = 0; i < 4; i++)
#pragma unroll
    for (int j = 0; j < 4; j++) acc[i][j] = zero4();

  for (int k0 = 0; k0 < K; k0 += 32) {
#pragma unroll
    for (int i = 0; i < 2; i++) {
      int seg = w * 2 + i;
      int bo = seg * 1024 + lane * 16;
      int row = bo >> 6, col = (bo & 63) >> 1;
      GLDS16(A + (size_t)(m0 + row) * K + k0 + col, (char*)As + seg * 1024);
      GLDS16(Bw + (size_t)(n0 + row) * K + k0 + col, (char*)Bs + seg * 1024);
    }
    __syncthreads();
    short8 af[4], bfr[4];
#pragma unroll
    for (int i = 0; i < 4; i++) {
      af[i] = *(const short8*)&As[(wm + i * 16 + c) * 32 + quad * 8];
      bfr[i] = *(const short8*)&Bs[(wn + i * 16 + c) * 32 + quad * 8];
    }
#pragma unroll
    for (int mi = 0; mi < 4; mi++)
#pragma unroll
      for (int ni = 0; ni < 4; ni++) acc[mi][ni] = MFMA16(af[mi], bfr[ni], acc[mi][ni]);
    __syncthreads();
  }
#pragma unroll
  for (int mi = 0; mi < 4; mi++) {
    int rowb = m0 + wm + mi * 16 + quad * 4;  // 4-aligned; r=0..3 never crosses a 64-boundary
    int b = rowb >> 12;
    int sk0 = rowb & 4095;
    int kt = sk0 >> 6, ki0 = sk0 & 63;
    int sg = ((wm + mi * 16) & 63) >> 4;  // ki>>4, constant over quad/r
    int khi = quad >> 1;                  // (ki>>3)&1
    int j0 = (quad & 1) * 4;              // ki&7 base; r adds 0..3
#pragma unroll
    for (int ni = 0; ni < 4; ni++) {
      int col = n0 + wn + ni * 16 + c;
      int h = col >> 7, rr = col & 127;
      size_t base = ((size_t)(b * 16 + h)) * 262144 + (size_t)kt * 4096;
      if (rr < 64) {
        int d = rr;
        int ds = d >> 4, dhi = (d >> 3) & 1, j = d & 7;
#pragma unroll
        for (int r = 0; r < 4; r++) {
          int ki = ki0 + r;
          int half = ki >> 5, l31k = ki & 31;
          Kb[base + (size_t)((half * 4 + ds) * 64 + l31k + 32 * dhi) * 8 + j] = f2bf(acc[mi][ni][r]);
        }
      } else {
        int d = rr - 64;
        int dt = d >> 5;
        unsigned lo = (unsigned)f2bf(acc[mi][ni][0]) | ((unsigned)f2bf(acc[mi][ni][1]) << 16);
        unsigned hi = (unsigned)f2bf(acc[mi][ni][2]) | ((unsigned)f2bf(acc[mi][ni][3]) << 16);
        *(uint2*)(Vb + base + (size_t)((dt * 4 + sg) * 64 + (d & 31) + 32 * khi) * 8 + j0) =
            make_uint2(lo, hi);
      }
    }
  }
}

// ---------------------------------------------------------------- K4 compute body: one 64-key tile from (Kl,Vl)
__device__ __forceinline__ void attn_tile(const char* Kl, const char* Vl,
                                          const short8 (&qf)[4], f32x16 (&O)[2], float& lp) {
#pragma unroll
  for (int h = 0; h < 2; h++) {  // 32-key halves
    short8 kf[4];
#pragma unroll
    for (int ds = 0; ds < 4; ds++) kf[ds] = *(const short8*)(Kl + (h * 4 + ds) * 1024);
    f32x16 S = zero16();
    __builtin_amdgcn_s_setprio(1);  // T5: favor the MFMA-issuing wave
#pragma unroll
    for (int ds = 0; ds < 4; ds++) S = MFMA32(kf[ds], qf[ds], S);
    __builtin_amdgcn_s_setprio(0);
    float lpa = 0.f, lpb = 0.f;
    unsigned u[8];
#pragma unroll
    for (int m = 0; m < 8; m++) {
      float p0 = __builtin_amdgcn_exp2f(S[2 * m]);
      float p1 = __builtin_amdgcn_exp2f(S[2 * m + 1]);
      if (m & 1) lpb += p0 + p1; else lpa += p0 + p1;
      u[m] = cvtpk_bf16(p0, p1);
    }
    lp += lpa + lpb;
    // transpose to A-frag (T12): pair (u0,u2),(u1,u3),(u4,u6),(u5,u7) across lane halves
    plswap(u[0], u[2]);
    plswap(u[1], u[3]);
    plswap(u[4], u[6]);
    plswap(u[5], u[7]);
    u32x4 w0 = {u[0], u[1], u[2], u[3]};
    u32x4 w1 = {u[4], u[5], u[6], u[7]};
    short8 paf0 = __builtin_bit_cast(short8, w0);
    short8 paf1 = __builtin_bit_cast(short8, w1);
    // PV: O[dt] += P(16-key slice) V(slice)
    __builtin_amdgcn_s_setprio(1);
#pragma unroll
    for (int dt = 0; dt < 2; dt++) {
      short8 vf0 = *(const short8*)(Vl + (dt * 4 + h * 2 + 0) * 1024);
      short8 vf1 = *(const short8*)(Vl + (dt * 4 + h * 2 + 1) * 1024);
      O[dt] = MFMA32(paf0, vf0, O[dt]);
      O[dt] = MFMA32(paf1, vf1, O[dt]);
    }
    __builtin_amdgcn_s_setprio(0);
  }
}

// ---------------------------------------------------------------- K4: flash attention, 32x32x16 MFMA, P fully in-register.
// R6 structure (two distinct LDS buffers, stage-first, one __syncthreads per
// phase; all sync compiler-understood) + T5 setprio around MFMA clusters.
// Plateau diagnosis (R4/R5/R6 all ~147us): MfmaUtil 44 + VALUBusy 54 ~= 98% --
// the pipes alternate (QK->softmax->PV chain, barrier-aligned waves); time ~=
// MFMA-busy + VALU-busy. setprio lets drifted blocks' MFMA waves preempt
// softmax-phase waves (attn +4-7% per T5 catalog).
__global__ __launch_bounds__(256, 4) void k_attn(const unsigned short* __restrict__ Qb,
                                                 const unsigned short* __restrict__ Kb,
                                                 const unsigned short* __restrict__ Vb,
                                                 unsigned short* __restrict__ Ob) {
  __shared__ __align__(16) short KA[8192];  // 16 KiB: K 8KiB | V 8KiB (even tiles)
  __shared__ __align__(16) short KB[8192];  // odd tiles
  int tid = threadIdx.x;
  int w = tid >> 6, lane = tid & 63;
  int l31 = lane & 31, hi = lane >> 5;
  int qt = blockIdx.x, bh = blockIdx.y;

  const char* Kg = (const char*)Kb + (size_t)bh * 524288;
  const char* Vg = (const char*)Vb + (size_t)bh * 524288;
  // wave w stages 4 consecutive 1KiB segs: w=0,1 -> K segs 0-7; w=2,3 -> V segs 8-15
  int ldsseg = (w < 2) ? w * 4 : 8 + (w - 2) * 4;  // seg index within a 16 KiB buf
  const char* sgbase = ((w < 2) ? Kg + (w * 4) * 1024 : Vg + ((w - 2) * 4) * 1024) + lane * 16;

  // Q fragments (B-operand): lane holds Q[q = l31][d = ds*16 + hi*8 + 0..7]
  const unsigned short* Qrow = Qb + ((size_t)bh * 2048 + qt * 128 + w * 32 + l31) * 64 + hi * 8;
  short8 qf[4];
#pragma unroll
  for (int ds = 0; ds < 4; ds++) qf[ds] = *(const short8*)(Qrow + ds * 16);

  f32x16 O[2];
  float lp = 0.f;
#pragma unroll
  for (int j = 0; j < 2; j++) O[j] = zero16();

  // prologue: stage tile 0 -> KA
#pragma unroll
  for (int i = 0; i < 4; i++) GLDS16(sgbase + i * 1024, (char*)KA + (ldsseg + i) * 1024);
  sgbase += 8192;  // next tile to stage = 1
  __syncthreads();

  for (int kt2 = 0; kt2 < 64; kt2 += 2) {
    // ---- phase A: stage tile kt2+1 -> KB, compute tile kt2 from KA ----
    {
#pragma unroll
      for (int i = 0; i < 4; i++)
        GLDS16(sgbase + i * 1024, (char*)KB + (ldsseg + i) * 1024);
      sgbase += 8192;
      attn_tile((const char*)KA + lane * 16, (const char*)KA + lane * 16 + 8192, qf, O, lp);
      __syncthreads();  // drains stage (full compute of cover) + ds_reads + joins waves
    }
    // ---- phase B: stage tile kt2+2 -> KA, compute tile kt2+1 from KB ----
    {
      if (kt2 < 62) {
#pragma unroll
        for (int i = 0; i < 4; i++)
          GLDS16(sgbase + i * 1024, (char*)KA + (ldsseg + i) * 1024);
        sgbase += 8192;
      }
      attn_tile((const char*)KB + lane * 16, (const char*)KB + lane * 16 + 8192, qf, O, lp);
      __syncthreads();
    }
  }

  // lanes l and l+32 hold complementary key-partials for q = l&31
  lp += __shfl_xor(lp, 32, 64);
  int b = bh >> 4, hh = bh & 15;
#pragma unroll
  for (int r = 0; r < 16; r++) {
    int qrow = (r & 3) + 8 * (r >> 2) + 4 * hi;
    float inv = __builtin_amdgcn_rcpf(__shfl(lp, qrow, 64));
    size_t orow = ((size_t)b * 2048 + qt * 128 + w * 32 + qrow) * 1024 + hh * 64 + l31;
    Ob[orow] = f2bf(O[0][r] * inv);
    Ob[orow + 32] = f2bf(O[1][r] * inv);
  }
}

// ---------------------------------------------------------------- K5: out = O @ Wout^T -> fp32
__global__ __launch_bounds__(256, 2) void k_out(const unsigned short* __restrict__ A,
                                                const unsigned short* __restrict__ Bw,
                                                float* __restrict__ Out) {
  __shared__ __align__(16) short As[128 * 32];
  __shared__ __align__(16) short Bs[128 * 32];
  const int K = 1024;
  int tid = threadIdx.x;
  int w = tid >> 6, lane = tid & 63, quad = lane >> 4, c = lane & 15;
  int m0 = blockIdx.x * 128, n0 = blockIdx.y * 128;
  int wm = (w >> 1) * 64, wn = (w & 1) * 64;
  f32x4 acc[4][4];
#pragma unroll
  for (int i = 0; i < 4; i++)
#pragma unroll
    for (int j = 0; j < 4; j++) acc[i][j] = zero4();

  for (int k0 = 0; k0 < K; k0 += 32) {
#pragma unroll
    for (int i = 0; i < 2; i++) {
      int seg = w * 2 + i;
      int bo = seg * 1024 + lane * 16;
      int row = bo >> 6, col = (bo & 63) >> 1;
      GLDS16(A + (size_t)(m0 + row) * K + k0 + col, (char*)As + seg * 1024);
      GLDS16(Bw + (size_t)(n0 + row) * K + k0 + col, (char*)Bs + seg * 1024);
    }
    __syncthreads();
    short8 af[4], bfr[4];
#pragma unroll
    for (int i = 0; i < 4; i++) {
      af[i] = *(const short8*)&As[(wm + i * 16 + c) * 32 + quad * 8];
      bfr[i] = *(const short8*)&Bs[(wn + i * 16 + c) * 32 + quad * 8];
    }
#pragma unroll
    for (int mi = 0; mi < 4; mi++)
#pragma unroll
      for (int ni = 0; ni < 4; ni++) acc[mi][ni] = MFMA16(af[mi], bfr[ni], acc[mi][ni]);
    __syncthreads();
  }
#pragma unroll
  for (int mi = 0; mi < 4; mi++) {
    int rowb = m0 + wm + mi * 16 + quad * 4;
#pragma unroll
    for (int ni = 0; ni < 4; ni++) {
      int col = n0 + wn + ni * 16 + c;
#pragma unroll
      for (int r = 0; r < 4; r++) Out[(size_t)(rowb + r) * 1024 + col] = acc[mi][ni][r];
    }
  }
}

// ---------------------------------------------------------------- launch
extern "C" void kernel_launch(void* const* d_in, const int* in_sizes, int n_in,
                              void* d_out, int out_size, void* d_ws, size_t ws_size,
                              hipStream_t stream) {
  const float* query = (const float*)d_in[0];
  const float* enc = (const float*)d_in[1];
  const float* Wq = (const float*)d_in[2];
  const float* Wkva = (const float*)d_in[3];
  const float* ln_g = (const float*)d_in[4];
  const float* ln_b = (const float*)d_in[5];
  const float* Wkvb = (const float*)d_in[6];
  const float* Wout = (const float*)d_in[7];
  if (ws_size < 81264640) return;  // need ~77.5 MB scratch

  char* ws = (char*)d_ws;
  unsigned short* wq_bf = (unsigned short*)(ws + 0);         // 2 MB
  unsigned short* wa_bf = (unsigned short*)(ws + 2097152);   // 512 KB
  unsigned short* wb_bf = (unsigned short*)(ws + 2621440);   // 1 MB
  unsigned short* wo_bf = (unsigned short*)(ws + 3670016);   // 2 MB
  unsigned short* qproj = (unsigned short*)(ws + 5767168);   // 16 MB (B,H,SQ,64)
  unsigned short* cln = (unsigned short*)(ws + 22544384);    // 8 MB
  unsigned short* vbuf = (unsigned short*)(ws + 30932992);   // 32 MB: V tiles
  unsigned short* obuf = (unsigned short*)(ws + 64487424);   // 16 MB: O bf16
  unsigned short* kbuf = (unsigned short*)d_out;             // 32 MB: K tiles until final GEMM

  k_cast4<<<2816, 256, 0, stream>>>(Wq, Wout, Wkvb, Wkva, wq_bf, wo_bf, wb_bf, wa_bf);

  k_qproj<<<dim3(64, 8), 256, 0, stream>>>(query, wq_bf, qproj);
  k_cln<<<256, 256, 0, stream>>>(enc, wa_bf, ln_g, ln_b, cln);
  k_kv<<<dim3(128, 16), 256, 0, stream>>>(cln, wb_bf, kbuf, vbuf);
  k_attn<<<dim3(16, 64), 256, 0, stream>>>(qproj, kbuf, vbuf, obuf);
  k_out<<<dim3(64, 8), 256, 0, stream>>>(obuf, wo_bf, (float*)d_out);
}

// Round 8
// 405.853 us; speedup vs baseline: 1.1232x; 1.1232x over previous
//
#include <hip/hip_runtime.h>

#define LOG2E 1.4426950408889634f

typedef __attribute__((ext_vector_type(8))) short short8;
typedef __attribute__((ext_vector_type(4))) float f32x4;
typedef __attribute__((ext_vector_type(16))) float f32x16;
typedef __attribute__((ext_vector_type(4))) unsigned u32x4;

__device__ inline unsigned short f2bf(float f) {
  unsigned u = __float_as_uint(f);
  u += 0x7fffu + ((u >> 16) & 1u);
  return (unsigned short)(u >> 16);
}

#define MFMA16(a, b, c) __builtin_amdgcn_mfma_f32_16x16x32_bf16((a), (b), (c), 0, 0, 0)
#define MFMA32(a, b, c) __builtin_amdgcn_mfma_f32_32x32x16_bf16((a), (b), (c), 0, 0, 0)

#define GLDS16(gp, lp)                                                              \
  __builtin_amdgcn_global_load_lds((const __attribute__((address_space(1))) void*)(gp), \
                                   (__attribute__((address_space(3))) void*)(lp), 16, 0, 0)

__device__ inline f32x4 zero4() {
  f32x4 z = {0.f, 0.f, 0.f, 0.f};
  return z;
}
__device__ inline f32x16 zero16() {
  f32x16 z = {0.f, 0.f, 0.f, 0.f, 0.f, 0.f, 0.f, 0.f, 0.f, 0.f, 0.f, 0.f, 0.f, 0.f, 0.f, 0.f};
  return z;
}
// dst.lo16 = bf16(a), dst.hi16 = bf16(b)  (RNE, same bits as f2bf)
__device__ inline unsigned cvtpk_bf16(float a, float b) {
  unsigned r;
  asm("v_cvt_pk_bf16_f32 %0, %1, %2" : "=v"(r) : "v"(a), "v"(b));
  return r;
}
// after: a = [a.lo32lanes, b.lo32lanes], b = [a.hi32lanes, b.hi32lanes]
__device__ inline void plswap(unsigned& a, unsigned& b) {
  asm("v_permlane32_swap_b32 %0, %1" : "+v"(a), "+v"(b));
}

// ---------------------------------------------------------------- cast fp32 -> bf16: query + 4 weights (E fused into k_cln)
__global__ __launch_bounds__(256) void k_cast5(
    const float* __restrict__ q, const float* __restrict__ wq, const float* __restrict__ wo,
    const float* __restrict__ wb, const float* __restrict__ wa,
    unsigned short* __restrict__ qo, unsigned short* __restrict__ wqo, unsigned short* __restrict__ woo,
    unsigned short* __restrict__ wbo, unsigned short* __restrict__ wao) {
  int i = (blockIdx.x * 256 + threadIdx.x) * 4;
  const float* src;
  unsigned short* dst;
  int off;
  if (i < 8388608) { src = q; dst = qo; off = i; }
  else if (i < 9437184) { src = wq; dst = wqo; off = i - 8388608; }
  else if (i < 10485760) { src = wo; dst = woo; off = i - 9437184; }
  else if (i < 11010048) { src = wb; dst = wbo; off = i - 10485760; }
  else { src = wa; dst = wao; off = i - 11010048; }
  float4 v = *(const float4*)(src + off);
  unsigned lo = (unsigned)f2bf(v.x) | ((unsigned)f2bf(v.y) << 16);
  unsigned hi = (unsigned)f2bf(v.z) | ((unsigned)f2bf(v.w) << 16);
  *(uint2*)(dst + off) = make_uint2(lo, hi);
}

// ---------------------------------------------------------------- K1: q = query @ Wq^T (scaled by log2e/8), -> (B,H,SQ,64) bf16
// (R6-proven bf16/GLDS version: the R7 fp32-fused A-side amplified query reads
// 8x across n-blocks -> L2/L3 trash -> global regression. Reverted.)
__global__ __launch_bounds__(256, 2) void k_qproj(const unsigned short* __restrict__ A,
                                                  const unsigned short* __restrict__ Bw,
                                                  unsigned short* __restrict__ Qout) {
  __shared__ __align__(16) short As[128 * 32];
  __shared__ __align__(16) short Bs[128 * 32];
  const int K = 1024;
  int tid = threadIdx.x;
  int w = tid >> 6, lane = tid & 63, quad = lane >> 4, c = lane & 15;
  int m0 = blockIdx.x * 128, n0 = blockIdx.y * 128;
  int wm = (w >> 1) * 64, wn = (w & 1) * 64;
  f32x4 acc[4][4];
#pragma unroll
  for (int i = 0; i < 4; i++)
#pragma unroll
    for (int j = 0; j < 4; j++) acc[i][j] = zero4();

  for (int k0 = 0; k0 < K; k0 += 32) {
#pragma unroll
    for (int i = 0; i < 2; i++) {
      int seg = w * 2 + i;
      int bo = seg * 1024 + lane * 16;
      int row = bo >> 6, col = (bo & 63) >> 1;
      GLDS16(A + (size_t)(m0 + row) * K + k0 + col, (char*)As + seg * 1024);
      GLDS16(Bw + (size_t)(n0 + row) * K + k0 + col, (char*)Bs + seg * 1024);
    }
    __syncthreads();
    short8 af[4], bfr[4];
#pragma unroll
    for (int i = 0; i < 4; i++) {
      af[i] = *(const short8*)&As[(wm + i * 16 + c) * 32 + quad * 8];
      bfr[i] = *(const short8*)&Bs[(wn + i * 16 + c) * 32 + quad * 8];
    }
#pragma unroll
    for (int mi = 0; mi < 4; mi++)
#pragma unroll
      for (int ni = 0; ni < 4; ni++) acc[mi][ni] = MFMA16(af[mi], bfr[ni], acc[mi][ni]);
    __syncthreads();
  }
  const float scale = 0.125f * LOG2E;
#pragma unroll
  for (int mi = 0; mi < 4; mi++) {
    int rowb = m0 + wm + mi * 16 + quad * 4;
#pragma unroll
    for (int ni = 0; ni < 4; ni++) {
      int col = n0 + wn + ni * 16 + c;
      int h = col >> 6, d = col & 63;
#pragma unroll
      for (int r = 0; r < 4; r++) {
        int row = rowb + r;
        int b = row >> 11, sq = row & 2047;
        Qout[(((size_t)(b * 16 + h)) * 2048 + sq) * 64 + d] = f2bf(acc[mi][ni][r] * scale);
      }
    }
  }
}

// ---------------------------------------------------------------- K2: c = enc(fp32) @ Wkva^T, LayerNorm -> [16384,256] bf16
// E side reads fp32 directly (reg-stage + cvt_pk + ds_write_b128). NO read
// amplification here (grid covers all 256 N-cols in one block), so this fusion
// is clean: saves the standalone cast's 64MB read + 32MB write + 32MB re-read.
__global__ __launch_bounds__(256, 2) void k_cln(const float* __restrict__ E,
                                                const unsigned short* __restrict__ Wa,
                                                const float* __restrict__ g, const float* __restrict__ bb,
                                                unsigned short* __restrict__ Cout) {
  __shared__ __align__(16) short As[64 * 32];
  __shared__ __align__(16) short Bs[256 * 32];
  __shared__ float redS[4][64], redQ[4][64];
  __shared__ float gS[256], bS[256];
  const int K = 1024;
  int tid = threadIdx.x;
  int w = tid >> 6, lane = tid & 63, quad = lane >> 4, c = lane & 15;
  int m0 = blockIdx.x * 64;
  int rsub = lane >> 2, csub = (lane & 3) * 8;
  gS[tid] = g[tid];
  bS[tid] = bb[tid];
  f32x4 acc[4][4];
#pragma unroll
  for (int i = 0; i < 4; i++)
#pragma unroll
    for (int j = 0; j < 4; j++) acc[i][j] = zero4();

  for (int k0 = 0; k0 < K; k0 += 32) {
    {
      const float* Ep = E + (size_t)(m0 + w * 16 + rsub) * K + k0 + csub;
      float4 va = *(const float4*)Ep;
      float4 vb2 = *(const float4*)(Ep + 4);
      u32x4 pk = {cvtpk_bf16(va.x, va.y), cvtpk_bf16(va.z, va.w),
                  cvtpk_bf16(vb2.x, vb2.y), cvtpk_bf16(vb2.z, vb2.w)};
      *(u32x4*)((char*)As + w * 1024 + lane * 16) = pk;
    }
#pragma unroll
    for (int i = 0; i < 4; i++) {
      int seg = w * 4 + i;
      int bo = seg * 1024 + lane * 16;
      int row = bo >> 6, col = (bo & 63) >> 1;
      GLDS16(Wa + (size_t)row * K + k0 + col, (char*)Bs + seg * 1024);
    }
    __syncthreads();
    short8 af[4], bfr[4];
#pragma unroll
    for (int i = 0; i < 4; i++) {
      af[i] = *(const short8*)&As[(i * 16 + c) * 32 + quad * 8];
      bfr[i] = *(const short8*)&Bs[(w * 64 + i * 16 + c) * 32 + quad * 8];
    }
#pragma unroll
    for (int mi = 0; mi < 4; mi++)
#pragma unroll
      for (int ni = 0; ni < 4; ni++) acc[mi][ni] = MFMA16(af[mi], bfr[ni], acc[mi][ni]);
    __syncthreads();
  }
  float ps[4][4], pq[4][4];
#pragma unroll
  for (int mi = 0; mi < 4; mi++)
#pragma unroll
    for (int r = 0; r < 4; r++) {
      float s = 0.f, q = 0.f;
#pragma unroll
      for (int ni = 0; ni < 4; ni++) {
        float x = acc[mi][ni][r];
        s += x;
        q += x * x;
      }
      for (int m = 1; m < 16; m <<= 1) {
        s += __shfl_xor(s, m, 64);
        q += __shfl_xor(q, m, 64);
      }
      ps[mi][r] = s;
      pq[mi][r] = q;
    }
  if (c == 0) {
#pragma unroll
    for (int mi = 0; mi < 4; mi++)
#pragma unroll
      for (int r = 0; r < 4; r++) {
        int row = mi * 16 + quad * 4 + r;
        redS[w][row] = ps[mi][r];
        redQ[w][row] = pq[mi][r];
      }
  }
  __syncthreads();
  float muv[4][4], rsv[4][4];
#pragma unroll
  for (int mi = 0; mi < 4; mi++)
#pragma unroll
    for (int r = 0; r < 4; r++) {
      int row = mi * 16 + quad * 4 + r;
      float S = redS[0][row] + redS[1][row] + redS[2][row] + redS[3][row];
      float Q = redQ[0][row] + redQ[1][row] + redQ[2][row] + redQ[3][row];
      float mu = S * (1.f / 256.f);
      float var = Q * (1.f / 256.f) - mu * mu;
      muv[mi][r] = mu;
      rsv[mi][r] = rsqrtf(var + 1e-5f);
    }
#pragma unroll
  for (int mi = 0; mi < 4; mi++)
#pragma unroll
    for (int ni = 0; ni < 4; ni++) {
      int col = w * 64 + ni * 16 + c;
#pragma unroll
      for (int r = 0; r < 4; r++) {
        int row = m0 + mi * 16 + quad * 4 + r;
        float y = (acc[mi][ni][r] - muv[mi][r]) * rsv[mi][r] * gS[col] + bS[col];
        Cout[(size_t)row * 256 + col] = f2bf(y);
      }
    }
}

// ---------------------------------------------------------------- K3: kv = c_ln @ Wkvb^T -> K, V in attn fragment-major tiles
//  K: per bh, per 64-key tile: [(half*4 + ds)*64 + (key&31) + 32*((d>>3)&1)]*8 + (d&7)
//  V: [(dt*4 + s)*64 + (d&31) + 32*((k>>3)&1)]*8 + (k&7)
// V-store packed (kept from R7, correctness-verified): a lane's 4 r-values are
// 4 consecutive j-slots (j = (quad&1)*4 + r) -> one 8B uint2 store replaces 4
// scalar 2B scatter stores (1/8 write efficiency -> ~1 on 32 MB).
__global__ __launch_bounds__(256, 2) void k_kv(const unsigned short* __restrict__ A,
                                               const unsigned short* __restrict__ Bw,
                                               unsigned short* __restrict__ Kb,
                                               unsigned short* __restrict__ Vb) {
  __shared__ __align__(16) short As[128 * 32];
  __shared__ __align__(16) short Bs[128 * 32];
  const int K = 256;
  int tid = threadIdx.x;
  int w = tid >> 6, lane = tid & 63, quad = lane >> 4, c = lane & 15;
  int m0 = blockIdx.x * 128, n0 = blockIdx.y * 128;
  int wm = (w >> 1) * 64, wn = (w & 1) * 64;
  f32x4 acc[4][4];
#pragma unroll
  for (int i = 0; i < 4; i++)
#pragma unroll
    for (int j = 0; j < 4; j++) acc[i][j] = zero4();

  for (int k0 = 0; k0 < K; k0 += 32) {
#pragma unroll
    for (int i = 0; i < 2; i++) {
      int seg = w * 2 + i;
      int bo = seg * 1024 + lane * 16;
      int row = bo >> 6, col = (bo & 63) >> 1;
      GLDS16(A + (size_t)(m0 + row) * K + k0 + col, (char*)As + seg * 1024);
      GLDS16(Bw + (size_t)(n0 + row) * K + k0 + col, (char*)Bs + seg * 1024);
    }
    __syncthreads();
    short8 af[4], bfr[4];
#pragma unroll
    for (int i = 0; i < 4; i++) {
      af[i] = *(const short8*)&As[(wm + i * 16 + c) * 32 + quad * 8];
      bfr[i] = *(const short8*)&Bs[(wn + i * 16 + c) * 32 + quad * 8];
    }
#pragma unroll
    for (int mi = 0; mi < 4; mi++)
#pragma unroll
      for (int ni = 0; ni < 4; ni++) acc[mi][ni] = MFMA16(af[mi], bfr[ni], acc[mi][ni]);
    __syncthreads();
  }
#pragma unroll
  for (int mi = 0; mi < 4; mi++) {
    int rowb = m0 + wm + mi * 16 + quad * 4;  // 4-aligned; r=0..3 never crosses a 64-boundary
    int b = rowb >> 12;
    int sk0 = rowb & 4095;
    int kt = sk0 >> 6, ki0 = sk0 & 63;
    int sg = ((wm + mi * 16) & 63) >> 4;  // ki>>4, constant over quad/r
    int khi = quad >> 1;                  // (ki>>3)&1
    int j0 = (quad & 1) * 4;              // ki&7 base; r adds 0..3
#pragma unroll
    for (int ni = 0; ni < 4; ni++) {
      int col = n0 + wn + ni * 16 + c;
      int h = col >> 7, rr = col & 127;
      size_t base = ((size_t)(b * 16 + h)) * 262144 + (size_t)kt * 4096;
      if (rr < 64) {
        int d = rr;
        int ds = d >> 4, dhi = (d >> 3) & 1, j = d & 7;
#pragma unroll
        for (int r = 0; r < 4; r++) {
          int ki = ki0 + r;
          int half = ki >> 5, l31k = ki & 31;
          Kb[base + (size_t)((half * 4 + ds) * 64 + l31k + 32 * dhi) * 8 + j] = f2bf(acc[mi][ni][r]);
        }
      } else {
        int d = rr - 64;
        int dt = d >> 5;
        unsigned lo = (unsigned)f2bf(acc[mi][ni][0]) | ((unsigned)f2bf(acc[mi][ni][1]) << 16);
        unsigned hi = (unsigned)f2bf(acc[mi][ni][2]) | ((unsigned)f2bf(acc[mi][ni][3]) << 16);
        *(uint2*)(Vb + base + (size_t)((dt * 4 + sg) * 64 + (d & 31) + 32 * khi) * 8 + j0) =
            make_uint2(lo, hi);
      }
    }
  }
}

// ---------------------------------------------------------------- K4 compute body: one 64-key tile from (Kl,Vl)  (pure R6, no setprio)
__device__ __forceinline__ void attn_tile(const char* Kl, const char* Vl,
                                          const short8 (&qf)[4], f32x16 (&O)[2], float& lp) {
#pragma unroll
  for (int h = 0; h < 2; h++) {  // 32-key halves
    short8 kf[4];
#pragma unroll
    for (int ds = 0; ds < 4; ds++) kf[ds] = *(const short8*)(Kl + (h * 4 + ds) * 1024);
    f32x16 S = zero16();
#pragma unroll
    for (int ds = 0; ds < 4; ds++) S = MFMA32(kf[ds], qf[ds], S);
    float lpa = 0.f, lpb = 0.f;
    unsigned u[8];
#pragma unroll
    for (int m = 0; m < 8; m++) {
      float p0 = __builtin_amdgcn_exp2f(S[2 * m]);
      float p1 = __builtin_amdgcn_exp2f(S[2 * m + 1]);
      if (m & 1) lpb += p0 + p1; else lpa += p0 + p1;
      u[m] = cvtpk_bf16(p0, p1);
    }
    lp += lpa + lpb;
    // transpose to A-frag (T12): pair (u0,u2),(u1,u3),(u4,u6),(u5,u7) across lane halves
    plswap(u[0], u[2]);
    plswap(u[1], u[3]);
    plswap(u[4], u[6]);
    plswap(u[5], u[7]);
    u32x4 w0 = {u[0], u[1], u[2], u[3]};
    u32x4 w1 = {u[4], u[5], u[6], u[7]};
    short8 paf0 = __builtin_bit_cast(short8, w0);
    short8 paf1 = __builtin_bit_cast(short8, w1);
    // PV: O[dt] += P(16-key slice) V(slice)
#pragma unroll
    for (int dt = 0; dt < 2; dt++) {
      short8 vf0 = *(const short8*)(Vl + (dt * 4 + h * 2 + 0) * 1024);
      short8 vf1 = *(const short8*)(Vl + (dt * 4 + h * 2 + 1) * 1024);
      O[dt] = MFMA32(paf0, vf0, O[dt]);
      O[dt] = MFMA32(paf1, vf1, O[dt]);
    }
  }
}

// ---------------------------------------------------------------- K4: flash attention (pure R6 structure: two distinct LDS
// buffers, stage-first, one __syncthreads per phase, compiler-understood sync only; setprio removed with R7's regression).
__global__ __launch_bounds__(256, 4) void k_attn(const unsigned short* __restrict__ Qb,
                                                 const unsigned short* __restrict__ Kb,
                                                 const unsigned short* __restrict__ Vb,
                                                 unsigned short* __restrict__ Ob) {
  __shared__ __align__(16) short KA[8192];  // 16 KiB: K 8KiB | V 8KiB (even tiles)
  __shared__ __align__(16) short KB[8192];  // odd tiles
  int tid = threadIdx.x;
  int w = tid >> 6, lane = tid & 63;
  int l31 = lane & 31, hi = lane >> 5;
  int qt = blockIdx.x, bh = blockIdx.y;

  const char* Kg = (const char*)Kb + (size_t)bh * 524288;
  const char* Vg = (const char*)Vb + (size_t)bh * 524288;
  // wave w stages 4 consecutive 1KiB segs: w=0,1 -> K segs 0-7; w=2,3 -> V segs 8-15
  int ldsseg = (w < 2) ? w * 4 : 8 + (w - 2) * 4;  // seg index within a 16 KiB buf
  const char* sgbase = ((w < 2) ? Kg + (w * 4) * 1024 : Vg + ((w - 2) * 4) * 1024) + lane * 16;

  // Q fragments (B-operand): lane holds Q[q = l31][d = ds*16 + hi*8 + 0..7]
  const unsigned short* Qrow = Qb + ((size_t)bh * 2048 + qt * 128 + w * 32 + l31) * 64 + hi * 8;
  short8 qf[4];
#pragma unroll
  for (int ds = 0; ds < 4; ds++) qf[ds] = *(const short8*)(Qrow + ds * 16);

  f32x16 O[2];
  float lp = 0.f;
#pragma unroll
  for (int j = 0; j < 2; j++) O[j] = zero16();

  // prologue: stage tile 0 -> KA
#pragma unroll
  for (int i = 0; i < 4; i++) GLDS16(sgbase + i * 1024, (char*)KA + (ldsseg + i) * 1024);
  sgbase += 8192;  // next tile to stage = 1
  __syncthreads();

  for (int kt2 = 0; kt2 < 64; kt2 += 2) {
    // ---- phase A: stage tile kt2+1 -> KB, compute tile kt2 from KA ----
    {
#pragma unroll
      for (int i = 0; i < 4; i++)
        GLDS16(sgbase + i * 1024, (char*)KB + (ldsseg + i) * 1024);
      sgbase += 8192;
      attn_tile((const char*)KA + lane * 16, (const char*)KA + lane * 16 + 8192, qf, O, lp);
      __syncthreads();  // drains stage (full compute of cover) + ds_reads + joins waves
    }
    // ---- phase B: stage tile kt2+2 -> KA, compute tile kt2+1 from KB ----
    {
      if (kt2 < 62) {
#pragma unroll
        for (int i = 0; i < 4; i++)
          GLDS16(sgbase + i * 1024, (char*)KA + (ldsseg + i) * 1024);
        sgbase += 8192;
      }
      attn_tile((const char*)KB + lane * 16, (const char*)KB + lane * 16 + 8192, qf, O, lp);
      __syncthreads();
    }
  }

  // lanes l and l+32 hold complementary key-partials for q = l&31
  lp += __shfl_xor(lp, 32, 64);
  int b = bh >> 4, hh = bh & 15;
#pragma unroll
  for (int r = 0; r < 16; r++) {
    int qrow = (r & 3) + 8 * (r >> 2) + 4 * hi;
    float inv = __builtin_amdgcn_rcpf(__shfl(lp, qrow, 64));
    size_t orow = ((size_t)b * 2048 + qt * 128 + w * 32 + qrow) * 1024 + hh * 64 + l31;
    Ob[orow] = f2bf(O[0][r] * inv);
    Ob[orow + 32] = f2bf(O[1][r] * inv);
  }
}

// ---------------------------------------------------------------- K5: out = O @ Wout^T -> fp32
__global__ __launch_bounds__(256, 2) void k_out(const unsigned short* __restrict__ A,
                                                const unsigned short* __restrict__ Bw,
                                                float* __restrict__ Out) {
  __shared__ __align__(16) short As[128 * 32];
  __shared__ __align__(16) short Bs[128 * 32];
  const int K = 1024;
  int tid = threadIdx.x;
  int w = tid >> 6, lane = tid & 63, quad = lane >> 4, c = lane & 15;
  int m0 = blockIdx.x * 128, n0 = blockIdx.y * 128;
  int wm = (w >> 1) * 64, wn = (w & 1) * 64;
  f32x4 acc[4][4];
#pragma unroll
  for (int i = 0; i < 4; i++)
#pragma unroll
    for (int j = 0; j < 4; j++) acc[i][j] = zero4();

  for (int k0 = 0; k0 < K; k0 += 32) {
#pragma unroll
    for (int i = 0; i < 2; i++) {
      int seg = w * 2 + i;
      int bo = seg * 1024 + lane * 16;
      int row = bo >> 6, col = (bo & 63) >> 1;
      GLDS16(A + (size_t)(m0 + row) * K + k0 + col, (char*)As + seg * 1024);
      GLDS16(Bw + (size_t)(n0 + row) * K + k0 + col, (char*)Bs + seg * 1024);
    }
    __syncthreads();
    short8 af[4], bfr[4];
#pragma unroll
    for (int i = 0; i < 4; i++) {
      af[i] = *(const short8*)&As[(wm + i * 16 + c) * 32 + quad * 8];
      bfr[i] = *(const short8*)&Bs[(wn + i * 16 + c) * 32 + quad * 8];
    }
#pragma unroll
    for (int mi = 0; mi < 4; mi++)
#pragma unroll
      for (int ni = 0; ni < 4; ni++) acc[mi][ni] = MFMA16(af[mi], bfr[ni], acc[mi][ni]);
    __syncthreads();
  }
#pragma unroll
  for (int mi = 0; mi < 4; mi++) {
    int rowb = m0 + wm + mi * 16 + quad * 4;
#pragma unroll
    for (int ni = 0; ni < 4; ni++) {
      int col = n0 + wn + ni * 16 + c;
#pragma unroll
      for (int r = 0; r < 4; r++) Out[(size_t)(rowb + r) * 1024 + col] = acc[mi][ni][r];
    }
  }
}

// ---------------------------------------------------------------- launch
extern "C" void kernel_launch(void* const* d_in, const int* in_sizes, int n_in,
                              void* d_out, int out_size, void* d_ws, size_t ws_size,
                              hipStream_t stream) {
  const float* query = (const float*)d_in[0];
  const float* enc = (const float*)d_in[1];
  const float* Wq = (const float*)d_in[2];
  const float* Wkva = (const float*)d_in[3];
  const float* ln_g = (const float*)d_in[4];
  const float* ln_b = (const float*)d_in[5];
  const float* Wkvb = (const float*)d_in[6];
  const float* Wout = (const float*)d_in[7];
  if (ws_size < 81264640) return;  // need ~77.5 MB scratch

  char* ws = (char*)d_ws;
  unsigned short* wq_bf = (unsigned short*)(ws + 0);         // 2 MB
  unsigned short* wa_bf = (unsigned short*)(ws + 2097152);   // 512 KB
  unsigned short* wb_bf = (unsigned short*)(ws + 2621440);   // 1 MB
  unsigned short* wo_bf = (unsigned short*)(ws + 3670016);   // 2 MB
  unsigned short* qproj = (unsigned short*)(ws + 5767168);   // 16 MB (B,H,SQ,64)
  unsigned short* cln = (unsigned short*)(ws + 22544384);    // 8 MB
  unsigned short* vbuf = (unsigned short*)(ws + 30932992);   // 32 MB: V tiles
  unsigned short* qin_o = (unsigned short*)(ws + 64487424);  // 16 MB: Q_in bf16, then O
  unsigned short* kbuf = (unsigned short*)d_out;             // 32 MB: K tiles until final GEMM

  k_cast5<<<11008, 256, 0, stream>>>(query, Wq, Wout, Wkvb, Wkva,
                                     qin_o, wq_bf, wo_bf, wb_bf, wa_bf);

  k_qproj<<<dim3(64, 8), 256, 0, stream>>>(qin_o, wq_bf, qproj);
  k_cln<<<256, 256, 0, stream>>>(enc, wa_bf, ln_g, ln_b, cln);
  k_kv<<<dim3(128, 16), 256, 0, stream>>>(cln, wb_bf, kbuf, vbuf);
  k_attn<<<dim3(16, 64), 256, 0, stream>>>(qproj, kbuf, vbuf, qin_o);
  k_out<<<dim3(64, 8), 256, 0, stream>>>(qin_o, wo_bf, (float*)d_out);
}

// Round 9
// 396.680 us; speedup vs baseline: 1.1492x; 1.0231x over previous
//
#include <hip/hip_runtime.h>

#define LOG2E 1.4426950408889634f

typedef __attribute__((ext_vector_type(8))) short short8;
typedef __attribute__((ext_vector_type(4))) float f32x4;
typedef __attribute__((ext_vector_type(16))) float f32x16;
typedef __attribute__((ext_vector_type(4))) unsigned u32x4;

__device__ inline unsigned short f2bf(float f) {
  unsigned u = __float_as_uint(f);
  u += 0x7fffu + ((u >> 16) & 1u);
  return (unsigned short)(u >> 16);
}

#define MFMA16(a, b, c) __builtin_amdgcn_mfma_f32_16x16x32_bf16((a), (b), (c), 0, 0, 0)
#define MFMA32(a, b, c) __builtin_amdgcn_mfma_f32_32x32x16_bf16((a), (b), (c), 0, 0, 0)

#define GLDS16(gp, lp)                                                              \
  __builtin_amdgcn_global_load_lds((const __attribute__((address_space(1))) void*)(gp), \
                                   (__attribute__((address_space(3))) void*)(lp), 16, 0, 0)

__device__ inline f32x4 zero4() {
  f32x4 z = {0.f, 0.f, 0.f, 0.f};
  return z;
}
__device__ inline f32x16 zero16() {
  f32x16 z = {0.f, 0.f, 0.f, 0.f, 0.f, 0.f, 0.f, 0.f, 0.f, 0.f, 0.f, 0.f, 0.f, 0.f, 0.f, 0.f};
  return z;
}
// dst.lo16 = bf16(a), dst.hi16 = bf16(b)  (RNE, same bits as f2bf)
__device__ inline unsigned cvtpk_bf16(float a, float b) {
  unsigned r;
  asm("v_cvt_pk_bf16_f32 %0, %1, %2" : "=v"(r) : "v"(a), "v"(b));
  return r;
}
// after: a = [a.lo32lanes, b.lo32lanes], b = [a.hi32lanes, b.hi32lanes]
__device__ inline void plswap(unsigned& a, unsigned& b) {
  asm("v_permlane32_swap_b32 %0, %1" : "+v"(a), "+v"(b));
}

// ---------------------------------------------------------------- cast fp32 -> bf16: query + 4 weights (E fused into k_cln)
__global__ __launch_bounds__(256) void k_cast5(
    const float* __restrict__ q, const float* __restrict__ wq, const float* __restrict__ wo,
    const float* __restrict__ wb, const float* __restrict__ wa,
    unsigned short* __restrict__ qo, unsigned short* __restrict__ wqo, unsigned short* __restrict__ woo,
    unsigned short* __restrict__ wbo, unsigned short* __restrict__ wao) {
  int i = (blockIdx.x * 256 + threadIdx.x) * 4;
  const float* src;
  unsigned short* dst;
  int off;
  if (i < 8388608) { src = q; dst = qo; off = i; }
  else if (i < 9437184) { src = wq; dst = wqo; off = i - 8388608; }
  else if (i < 10485760) { src = wo; dst = woo; off = i - 9437184; }
  else if (i < 11010048) { src = wb; dst = wbo; off = i - 10485760; }
  else { src = wa; dst = wao; off = i - 11010048; }
  float4 v = *(const float4*)(src + off);
  unsigned lo = (unsigned)f2bf(v.x) | ((unsigned)f2bf(v.y) << 16);
  unsigned hi = (unsigned)f2bf(v.z) | ((unsigned)f2bf(v.w) << 16);
  *(uint2*)(dst + off) = make_uint2(lo, hi);
}

// ---------------------------------------------------------------- K1+K2 fused: one launch, 768 blocks, interleaved 2:1.
// bx%3<2 -> qproj block (512 total), bx%3==2 -> cln block (256 total). Both kinds
// co-resident (2 blocks/CU capacity x 256 CU = 512 slots, mixed ~2:1) -- fixes
// k_cln's old 1-block/CU occupancy hole (grid 256 alone = 25% occupancy) and
// overlaps qproj's MFMA-heavy waves with cln's mixed waves (m114 co-schedule).
// LDS: single 24 KiB pool aliased per-branch (qproj 16K, cln 24K); blockIdx is
// block-uniform so branches never split a block (barriers safe).
__global__ __launch_bounds__(256, 2) void k_qc(
    const unsigned short* __restrict__ A, const unsigned short* __restrict__ Bw,
    unsigned short* __restrict__ Qout,
    const float* __restrict__ E, const unsigned short* __restrict__ Wa,
    const float* __restrict__ g, const float* __restrict__ bb,
    unsigned short* __restrict__ Cout) {
  __shared__ __align__(16) char pool[24576];
  int bx = blockIdx.x;
  int grp = bx / 3, rem = bx - grp * 3;
  int tid = threadIdx.x;
  int w = tid >> 6, lane = tid & 63, quad = lane >> 4, c = lane & 15;

  if (rem < 2) {
    // ---------------- qproj body (verbatim R8; qi in [0,512)) ----------------
    short* As = (short*)pool;            // 8 KiB
    short* Bs = (short*)(pool + 8192);   // 8 KiB
    int qi = grp * 2 + rem;
    const int K = 1024;
    int m0 = (qi >> 3) * 128, n0 = (qi & 7) * 128;
    int wm = (w >> 1) * 64, wn = (w & 1) * 64;
    f32x4 acc[4][4];
#pragma unroll
    for (int i = 0; i < 4; i++)
#pragma unroll
      for (int j = 0; j < 4; j++) acc[i][j] = zero4();

    for (int k0 = 0; k0 < K; k0 += 32) {
#pragma unroll
      for (int i = 0; i < 2; i++) {
        int seg = w * 2 + i;
        int bo = seg * 1024 + lane * 16;
        int row = bo >> 6, col = (bo & 63) >> 1;
        GLDS16(A + (size_t)(m0 + row) * K + k0 + col, (char*)As + seg * 1024);
        GLDS16(Bw + (size_t)(n0 + row) * K + k0 + col, (char*)Bs + seg * 1024);
      }
      __syncthreads();
      short8 af[4], bfr[4];
#pragma unroll
      for (int i = 0; i < 4; i++) {
        af[i] = *(const short8*)&As[(wm + i * 16 + c) * 32 + quad * 8];
        bfr[i] = *(const short8*)&Bs[(wn + i * 16 + c) * 32 + quad * 8];
      }
#pragma unroll
      for (int mi = 0; mi < 4; mi++)
#pragma unroll
        for (int ni = 0; ni < 4; ni++) acc[mi][ni] = MFMA16(af[mi], bfr[ni], acc[mi][ni]);
      __syncthreads();
    }
    const float scale = 0.125f * LOG2E;
#pragma unroll
    for (int mi = 0; mi < 4; mi++) {
      int rowb = m0 + wm + mi * 16 + quad * 4;
#pragma unroll
      for (int ni = 0; ni < 4; ni++) {
        int col = n0 + wn + ni * 16 + c;
        int h = col >> 6, d = col & 63;
#pragma unroll
        for (int r = 0; r < 4; r++) {
          int row = rowb + r;
          int b = row >> 11, sq = row & 2047;
          Qout[(((size_t)(b * 16 + h)) * 2048 + sq) * 64 + d] = f2bf(acc[mi][ni][r] * scale);
        }
      }
    }
  } else {
    // ---------------- cln body (verbatim R8; mi-block in [0,256)) ----------------
    short* As = (short*)pool;                      // 4 KiB
    short* Bs = (short*)(pool + 4096);             // 16 KiB
    float(*redS)[64] = (float(*)[64])(pool + 20480);  // 1 KiB
    float(*redQ)[64] = (float(*)[64])(pool + 21504);  // 1 KiB
    float* gS = (float*)(pool + 22528);            // 1 KiB
    float* bS = (float*)(pool + 23552);            // 1 KiB
    const int K = 1024;
    int m0 = grp * 64;
    int rsub = lane >> 2, csub = (lane & 3) * 8;
    gS[tid] = g[tid];
    bS[tid] = bb[tid];
    f32x4 acc[4][4];
#pragma unroll
    for (int i = 0; i < 4; i++)
#pragma unroll
      for (int j = 0; j < 4; j++) acc[i][j] = zero4();

    for (int k0 = 0; k0 < K; k0 += 32) {
      {
        const float* Ep = E + (size_t)(m0 + w * 16 + rsub) * K + k0 + csub;
        float4 va = *(const float4*)Ep;
        float4 vb2 = *(const float4*)(Ep + 4);
        u32x4 pk = {cvtpk_bf16(va.x, va.y), cvtpk_bf16(va.z, va.w),
                    cvtpk_bf16(vb2.x, vb2.y), cvtpk_bf16(vb2.z, vb2.w)};
        *(u32x4*)((char*)As + w * 1024 + lane * 16) = pk;
      }
#pragma unroll
      for (int i = 0; i < 4; i++) {
        int seg = w * 4 + i;
        int bo = seg * 1024 + lane * 16;
        int row = bo >> 6, col = (bo & 63) >> 1;
        GLDS16(Wa + (size_t)row * K + k0 + col, (char*)Bs + seg * 1024);
      }
      __syncthreads();
      short8 af[4], bfr[4];
#pragma unroll
      for (int i = 0; i < 4; i++) {
        af[i] = *(const short8*)&As[(i * 16 + c) * 32 + quad * 8];
        bfr[i] = *(const short8*)&Bs[(w * 64 + i * 16 + c) * 32 + quad * 8];
      }
#pragma unroll
      for (int mi = 0; mi < 4; mi++)
#pragma unroll
        for (int ni = 0; ni < 4; ni++) acc[mi][ni] = MFMA16(af[mi], bfr[ni], acc[mi][ni]);
      __syncthreads();
    }
    float ps[4][4], pq[4][4];
#pragma unroll
    for (int mi = 0; mi < 4; mi++)
#pragma unroll
      for (int r = 0; r < 4; r++) {
        float s = 0.f, q = 0.f;
#pragma unroll
        for (int ni = 0; ni < 4; ni++) {
          float x = acc[mi][ni][r];
          s += x;
          q += x * x;
        }
        for (int m = 1; m < 16; m <<= 1) {
          s += __shfl_xor(s, m, 64);
          q += __shfl_xor(q, m, 64);
        }
        ps[mi][r] = s;
        pq[mi][r] = q;
      }
    if (c == 0) {
#pragma unroll
      for (int mi = 0; mi < 4; mi++)
#pragma unroll
        for (int r = 0; r < 4; r++) {
          int row = mi * 16 + quad * 4 + r;
          redS[w][row] = ps[mi][r];
          redQ[w][row] = pq[mi][r];
        }
    }
    __syncthreads();
    float muv[4][4], rsv[4][4];
#pragma unroll
    for (int mi = 0; mi < 4; mi++)
#pragma unroll
      for (int r = 0; r < 4; r++) {
        int row = mi * 16 + quad * 4 + r;
        float S = redS[0][row] + redS[1][row] + redS[2][row] + redS[3][row];
        float Q = redQ[0][row] + redQ[1][row] + redQ[2][row] + redQ[3][row];
        float mu = S * (1.f / 256.f);
        float var = Q * (1.f / 256.f) - mu * mu;
        muv[mi][r] = mu;
        rsv[mi][r] = rsqrtf(var + 1e-5f);
      }
#pragma unroll
    for (int mi = 0; mi < 4; mi++)
#pragma unroll
      for (int ni = 0; ni < 4; ni++) {
        int col = w * 64 + ni * 16 + c;
#pragma unroll
        for (int r = 0; r < 4; r++) {
          int row = m0 + mi * 16 + quad * 4 + r;
          float y = (acc[mi][ni][r] - muv[mi][r]) * rsv[mi][r] * gS[col] + bS[col];
          Cout[(size_t)row * 256 + col] = f2bf(y);
        }
      }
  }
}

// ---------------------------------------------------------------- K3: kv = c_ln @ Wkvb^T -> K, V in attn fragment-major tiles
//  K: per bh, per 64-key tile: [(half*4 + ds)*64 + (key&31) + 32*((d>>3)&1)]*8 + (d&7)
//  V: [(dt*4 + s)*64 + (d&31) + 32*((k>>3)&1)]*8 + (k&7)
__global__ __launch_bounds__(256, 2) void k_kv(const unsigned short* __restrict__ A,
                                               const unsigned short* __restrict__ Bw,
                                               unsigned short* __restrict__ Kb,
                                               unsigned short* __restrict__ Vb) {
  __shared__ __align__(16) short As[128 * 32];
  __shared__ __align__(16) short Bs[128 * 32];
  const int K = 256;
  int tid = threadIdx.x;
  int w = tid >> 6, lane = tid & 63, quad = lane >> 4, c = lane & 15;
  int m0 = blockIdx.x * 128, n0 = blockIdx.y * 128;
  int wm = (w >> 1) * 64, wn = (w & 1) * 64;
  f32x4 acc[4][4];
#pragma unroll
  for (int i = 0; i < 4; i++)
#pragma unroll
    for (int j = 0; j < 4; j++) acc[i][j] = zero4();

  for (int k0 = 0; k0 < K; k0 += 32) {
#pragma unroll
    for (int i = 0; i < 2; i++) {
      int seg = w * 2 + i;
      int bo = seg * 1024 + lane * 16;
      int row = bo >> 6, col = (bo & 63) >> 1;
      GLDS16(A + (size_t)(m0 + row) * K + k0 + col, (char*)As + seg * 1024);
      GLDS16(Bw + (size_t)(n0 + row) * K + k0 + col, (char*)Bs + seg * 1024);
    }
    __syncthreads();
    short8 af[4], bfr[4];
#pragma unroll
    for (int i = 0; i < 4; i++) {
      af[i] = *(const short8*)&As[(wm + i * 16 + c) * 32 + quad * 8];
      bfr[i] = *(const short8*)&Bs[(wn + i * 16 + c) * 32 + quad * 8];
    }
#pragma unroll
    for (int mi = 0; mi < 4; mi++)
#pragma unroll
      for (int ni = 0; ni < 4; ni++) acc[mi][ni] = MFMA16(af[mi], bfr[ni], acc[mi][ni]);
    __syncthreads();
  }
#pragma unroll
  for (int mi = 0; mi < 4; mi++) {
    int rowb = m0 + wm + mi * 16 + quad * 4;
    int b = rowb >> 12;
    int sk0 = rowb & 4095;
    int kt = sk0 >> 6, ki0 = sk0 & 63;
    int sg = ((wm + mi * 16) & 63) >> 4;
    int khi = quad >> 1;
    int j0 = (quad & 1) * 4;
#pragma unroll
    for (int ni = 0; ni < 4; ni++) {
      int col = n0 + wn + ni * 16 + c;
      int h = col >> 7, rr = col & 127;
      size_t base = ((size_t)(b * 16 + h)) * 262144 + (size_t)kt * 4096;
      if (rr < 64) {
        int d = rr;
        int ds = d >> 4, dhi = (d >> 3) & 1, j = d & 7;
#pragma unroll
        for (int r = 0; r < 4; r++) {
          int ki = ki0 + r;
          int half = ki >> 5, l31k = ki & 31;
          Kb[base + (size_t)((half * 4 + ds) * 64 + l31k + 32 * dhi) * 8 + j] = f2bf(acc[mi][ni][r]);
        }
      } else {
        int d = rr - 64;
        int dt = d >> 5;
        unsigned lo = (unsigned)f2bf(acc[mi][ni][0]) | ((unsigned)f2bf(acc[mi][ni][1]) << 16);
        unsigned hi = (unsigned)f2bf(acc[mi][ni][2]) | ((unsigned)f2bf(acc[mi][ni][3]) << 16);
        *(uint2*)(Vb + base + (size_t)((dt * 4 + sg) * 64 + (d & 31) + 32 * khi) * 8 + j0) =
            make_uint2(lo, hi);
      }
    }
  }
}

// ---------------------------------------------------------------- K4 compute body: one 64-key tile from (Kl,Vl)
__device__ __forceinline__ void attn_tile(const char* Kl, const char* Vl,
                                          const short8 (&qf)[4], f32x16 (&O)[2], float& lp) {
#pragma unroll
  for (int h = 0; h < 2; h++) {  // 32-key halves
    short8 kf[4];
#pragma unroll
    for (int ds = 0; ds < 4; ds++) kf[ds] = *(const short8*)(Kl + (h * 4 + ds) * 1024);
    f32x16 S = zero16();
#pragma unroll
    for (int ds = 0; ds < 4; ds++) S = MFMA32(kf[ds], qf[ds], S);
    float lpa = 0.f, lpb = 0.f;
    unsigned u[8];
#pragma unroll
    for (int m = 0; m < 8; m++) {
      float p0 = __builtin_amdgcn_exp2f(S[2 * m]);
      float p1 = __builtin_amdgcn_exp2f(S[2 * m + 1]);
      if (m & 1) lpb += p0 + p1; else lpa += p0 + p1;
      u[m] = cvtpk_bf16(p0, p1);
    }
    lp += lpa + lpb;
    // transpose to A-frag (T12): pair (u0,u2),(u1,u3),(u4,u6),(u5,u7) across lane halves
    plswap(u[0], u[2]);
    plswap(u[1], u[3]);
    plswap(u[4], u[6]);
    plswap(u[5], u[7]);
    u32x4 w0 = {u[0], u[1], u[2], u[3]};
    u32x4 w1 = {u[4], u[5], u[6], u[7]};
    short8 paf0 = __builtin_bit_cast(short8, w0);
    short8 paf1 = __builtin_bit_cast(short8, w1);
    // PV: O[dt] += P(16-key slice) V(slice)
#pragma unroll
    for (int dt = 0; dt < 2; dt++) {
      short8 vf0 = *(const short8*)(Vl + (dt * 4 + h * 2 + 0) * 1024);
      short8 vf1 = *(const short8*)(Vl + (dt * 4 + h * 2 + 1) * 1024);
      O[dt] = MFMA32(paf0, vf0, O[dt]);
      O[dt] = MFMA32(paf1, vf1, O[dt]);
    }
  }
}

// ---------------------------------------------------------------- K4: flash attention (R6/R8 structure; at 76% of dense MFMA
// roofline -- 274.9 GFLOP / 144.4us = 1904 TF). R9 change: grid flipped to
// dim3(64,16) so XCD = linear_block_id & 7 = bh&7 -> each XCD's L2 working set
// drops from all 64 bh (64 MB) to 8 bh (8 MB); expect FETCH 270 -> ~140 MB.
__global__ __launch_bounds__(256, 4) void k_attn(const unsigned short* __restrict__ Qb,
                                                 const unsigned short* __restrict__ Kb,
                                                 const unsigned short* __restrict__ Vb,
                                                 unsigned short* __restrict__ Ob) {
  __shared__ __align__(16) short KA[8192];  // 16 KiB: K 8KiB | V 8KiB (even tiles)
  __shared__ __align__(16) short KB[8192];  // odd tiles
  int tid = threadIdx.x;
  int w = tid >> 6, lane = tid & 63;
  int l31 = lane & 31, hi = lane >> 5;
  int bh = blockIdx.x, qt = blockIdx.y;  // R9: bh fast-varying -> XCD groups by bh

  const char* Kg = (const char*)Kb + (size_t)bh * 524288;
  const char* Vg = (const char*)Vb + (size_t)bh * 524288;
  int ldsseg = (w < 2) ? w * 4 : 8 + (w - 2) * 4;
  const char* sgbase = ((w < 2) ? Kg + (w * 4) * 1024 : Vg + ((w - 2) * 4) * 1024) + lane * 16;

  const unsigned short* Qrow = Qb + ((size_t)bh * 2048 + qt * 128 + w * 32 + l31) * 64 + hi * 8;
  short8 qf[4];
#pragma unroll
  for (int ds = 0; ds < 4; ds++) qf[ds] = *(const short8*)(Qrow + ds * 16);

  f32x16 O[2];
  float lp = 0.f;
#pragma unroll
  for (int j = 0; j < 2; j++) O[j] = zero16();

  // prologue: stage tile 0 -> KA
#pragma unroll
  for (int i = 0; i < 4; i++) GLDS16(sgbase + i * 1024, (char*)KA + (ldsseg + i) * 1024);
  sgbase += 8192;
  __syncthreads();

  for (int kt2 = 0; kt2 < 64; kt2 += 2) {
    {
#pragma unroll
      for (int i = 0; i < 4; i++)
        GLDS16(sgbase + i * 1024, (char*)KB + (ldsseg + i) * 1024);
      sgbase += 8192;
      attn_tile((const char*)KA + lane * 16, (const char*)KA + lane * 16 + 8192, qf, O, lp);
      __syncthreads();
    }
    {
      if (kt2 < 62) {
#pragma unroll
        for (int i = 0; i < 4; i++)
          GLDS16(sgbase + i * 1024, (char*)KA + (ldsseg + i) * 1024);
        sgbase += 8192;
      }
      attn_tile((const char*)KB + lane * 16, (const char*)KB + lane * 16 + 8192, qf, O, lp);
      __syncthreads();
    }
  }

  lp += __shfl_xor(lp, 32, 64);
  int b = bh >> 4, hh = bh & 15;
#pragma unroll
  for (int r = 0; r < 16; r++) {
    int qrow = (r & 3) + 8 * (r >> 2) + 4 * hi;
    float inv = __builtin_amdgcn_rcpf(__shfl(lp, qrow, 64));
    size_t orow = ((size_t)b * 2048 + qt * 128 + w * 32 + qrow) * 1024 + hh * 64 + l31;
    Ob[orow] = f2bf(O[0][r] * inv);
    Ob[orow + 32] = f2bf(O[1][r] * inv);
  }
}

// ---------------------------------------------------------------- K5: out = O @ Wout^T -> fp32
__global__ __launch_bounds__(256, 2) void k_out(const unsigned short* __restrict__ A,
                                                const unsigned short* __restrict__ Bw,
                                                float* __restrict__ Out) {
  __shared__ __align__(16) short As[128 * 32];
  __shared__ __align__(16) short Bs[128 * 32];
  const int K = 1024;
  int tid = threadIdx.x;
  int w = tid >> 6, lane = tid & 63, quad = lane >> 4, c = lane & 15;
  int m0 = blockIdx.x * 128, n0 = blockIdx.y * 128;
  int wm = (w >> 1) * 64, wn = (w & 1) * 64;
  f32x4 acc[4][4];
#pragma unroll
  for (int i = 0; i < 4; i++)
#pragma unroll
    for (int j = 0; j < 4; j++) acc[i][j] = zero4();

  for (int k0 = 0; k0 < K; k0 += 32) {
#pragma unroll
    for (int i = 0; i < 2; i++) {
      int seg = w * 2 + i;
      int bo = seg * 1024 + lane * 16;
      int row = bo >> 6, col = (bo & 63) >> 1;
      GLDS16(A + (size_t)(m0 + row) * K + k0 + col, (char*)As + seg * 1024);
      GLDS16(Bw + (size_t)(n0 + row) * K + k0 + col, (char*)Bs + seg * 1024);
    }
    __syncthreads();
    short8 af[4], bfr[4];
#pragma unroll
    for (int i = 0; i < 4; i++) {
      af[i] = *(const short8*)&As[(wm + i * 16 + c) * 32 + quad * 8];
      bfr[i] = *(const short8*)&Bs[(wn + i * 16 + c) * 32 + quad * 8];
    }
#pragma unroll
    for (int mi = 0; mi < 4; mi++)
#pragma unroll
      for (int ni = 0; ni < 4; ni++) acc[mi][ni] = MFMA16(af[mi], bfr[ni], acc[mi][ni]);
    __syncthreads();
  }
#pragma unroll
  for (int mi = 0; mi < 4; mi++) {
    int rowb = m0 + wm + mi * 16 + quad * 4;
#pragma unroll
    for (int ni = 0; ni < 4; ni++) {
      int col = n0 + wn + ni * 16 + c;
#pragma unroll
      for (int r = 0; r < 4; r++) Out[(size_t)(rowb + r) * 1024 + col] = acc[mi][ni][r];
    }
  }
}

// ---------------------------------------------------------------- launch
extern "C" void kernel_launch(void* const* d_in, const int* in_sizes, int n_in,
                              void* d_out, int out_size, void* d_ws, size_t ws_size,
                              hipStream_t stream) {
  const float* query = (const float*)d_in[0];
  const float* enc = (const float*)d_in[1];
  const float* Wq = (const float*)d_in[2];
  const float* Wkva = (const float*)d_in[3];
  const float* ln_g = (const float*)d_in[4];
  const float* ln_b = (const float*)d_in[5];
  const float* Wkvb = (const float*)d_in[6];
  const float* Wout = (const float*)d_in[7];
  if (ws_size < 81264640) return;  // need ~77.5 MB scratch

  char* ws = (char*)d_ws;
  unsigned short* wq_bf = (unsigned short*)(ws + 0);         // 2 MB
  unsigned short* wa_bf = (unsigned short*)(ws + 2097152);   // 512 KB
  unsigned short* wb_bf = (unsigned short*)(ws + 2621440);   // 1 MB
  unsigned short* wo_bf = (unsigned short*)(ws + 3670016);   // 2 MB
  unsigned short* qproj = (unsigned short*)(ws + 5767168);   // 16 MB (B,H,SQ,64)
  unsigned short* cln = (unsigned short*)(ws + 22544384);    // 8 MB
  unsigned short* vbuf = (unsigned short*)(ws + 30932992);   // 32 MB: V tiles
  unsigned short* qin_o = (unsigned short*)(ws + 64487424);  // 16 MB: Q_in bf16, then O
  unsigned short* kbuf = (unsigned short*)d_out;             // 32 MB: K tiles until final GEMM

  k_cast5<<<11008, 256, 0, stream>>>(query, Wq, Wout, Wkvb, Wkva,
                                     qin_o, wq_bf, wo_bf, wb_bf, wa_bf);

  k_qc<<<768, 256, 0, stream>>>(qin_o, wq_bf, qproj, enc, wa_bf, ln_g, ln_b, cln);
  k_kv<<<dim3(128, 16), 256, 0, stream>>>(cln, wb_bf, kbuf, vbuf);
  k_attn<<<dim3(64, 16), 256, 0, stream>>>(qproj, kbuf, vbuf, qin_o);
  k_out<<<dim3(64, 8), 256, 0, stream>>>(qin_o, wo_bf, (float*)d_out);
}